// Round 1
// baseline (436.180 us; speedup 1.0000x reference)
//
#include <hip/hip_runtime.h>
#include <hip/hip_bf16.h>

// Per-token-group (G=128) fp8-range quantization:
//   y = clip(x / (max(amax,1e-4)/448), -448, 448)  [fp32], scale = amax/448.
//   d_out = [ y (MN fp32) | scale (MN/128 fp32) ].
//
// V2 (vectorized): one 16-lane sub-wave per group.
//  * 8 bf16 per lane via one 16 B load (int4); fp32 fallback via 2x float4
//  * group amax = per-lane max(8) + 4-step __shfl_xor over the 16-lane group
//    (no LDS, no barriers in the hot loop)
//  * 2x aligned float4 stores per lane (32 B/lane)
//  * 256-thread blocks, 16 groups per iteration, grid-stride at 2048 blocks
//  * runtime input-dtype vote kept verbatim from the verified V1 (bf16 packed
//    vs upcast-fp32 detection on the first 64 words; once per block)

static constexpr float FP8_MAX_F  = 448.0f;
static constexpr float AMAX_FLOOR = 1e-4f;

typedef float floatx4 __attribute__((ext_vector_type(4)));

__global__ __launch_bounds__(256) void quant_v2_kernel(
    const void* __restrict__ xraw,
    float* __restrict__ y,
    float* __restrict__ scale,
    long long n_groups)
{
    __shared__ int flag_s;

    // --- input dtype vote (same 64 words for every block; L3-resident) ---
    if (threadIdx.x < 64) {
        const unsigned int w  = ((const unsigned int*)xraw)[threadIdx.x];
        const bool lo_nonzero = (w & 0xffffu) != 0u;   // true => packed bf16
        unsigned long long m  = __ballot(lo_nonzero);
        if (threadIdx.x == 0) flag_s = (__popcll(m) >= 32) ? 1 : 0;
    }
    __syncthreads();
    const bool in_bf16 = (flag_s != 0);

    const int lane16 = threadIdx.x & 15;   // position within the group (8 elems each)
    const int gsub   = threadIdx.x >> 4;   // which of the 16 groups this block-iter
    const long long tiles = (n_groups + 15) >> 4;

    for (long long tile = blockIdx.x; tile < tiles; tile += gridDim.x) {
        const long long gid = tile * 16 + gsub;
        if (gid >= n_groups) continue;          // no barriers below -> safe

        const long long base = gid * 128 + (long long)lane16 * 8;  // element offset

        float v[8];
        if (in_bf16) {
            // 16 B = 8 bf16. base*2 bytes is 16B-aligned (base % 8 == 0).
            const int4 raw = *(const int4*)((const __hip_bfloat16*)xraw + base);
            const unsigned int* wp = (const unsigned int*)&raw;
#pragma unroll
            for (int i = 0; i < 4; ++i) {
                const unsigned int w = wp[i];
                v[2 * i]     = __uint_as_float((w & 0xffffu) << 16);  // low bf16
                v[2 * i + 1] = __uint_as_float(w & 0xffff0000u);      // high bf16
            }
        } else {
            const floatx4 a = ((const floatx4*)((const float*)xraw + base))[0];
            const floatx4 b = ((const floatx4*)((const float*)xraw + base))[1];
            v[0] = a.x; v[1] = a.y; v[2] = a.z; v[3] = a.w;
            v[4] = b.x; v[5] = b.y; v[6] = b.z; v[7] = b.w;
        }

        // --- per-lane abs-max over 8, then 16-lane butterfly reduce ---
        float m = fabsf(v[0]);
#pragma unroll
        for (int i = 1; i < 8; ++i) m = fmaxf(m, fabsf(v[i]));
        m = fmaxf(m, __shfl_xor(m, 1));
        m = fmaxf(m, __shfl_xor(m, 2));
        m = fmaxf(m, __shfl_xor(m, 4));
        m = fmaxf(m, __shfl_xor(m, 8));

        const float amax = fmaxf(m, AMAX_FLOOR);
        const float s    = amax * (1.0f / FP8_MAX_F);
        const float inv  = FP8_MAX_F / amax;   // same numerics as verified V1

        floatx4 o0, o1;
        o0.x = fminf(fmaxf(v[0] * inv, -FP8_MAX_F), FP8_MAX_F);
        o0.y = fminf(fmaxf(v[1] * inv, -FP8_MAX_F), FP8_MAX_F);
        o0.z = fminf(fmaxf(v[2] * inv, -FP8_MAX_F), FP8_MAX_F);
        o0.w = fminf(fmaxf(v[3] * inv, -FP8_MAX_F), FP8_MAX_F);
        o1.x = fminf(fmaxf(v[4] * inv, -FP8_MAX_F), FP8_MAX_F);
        o1.y = fminf(fmaxf(v[5] * inv, -FP8_MAX_F), FP8_MAX_F);
        o1.z = fminf(fmaxf(v[6] * inv, -FP8_MAX_F), FP8_MAX_F);
        o1.w = fminf(fmaxf(v[7] * inv, -FP8_MAX_F), FP8_MAX_F);

        ((floatx4*)(y + base))[0] = o0;
        ((floatx4*)(y + base))[1] = o1;

        if (lane16 == 0) scale[gid] = s;
    }
}

extern "C" void kernel_launch(void* const* d_in, const int* in_sizes, int n_in,
                              void* d_out, int out_size, void* d_ws, size_t ws_size,
                              hipStream_t stream) {
    const long long MN = (long long)in_sizes[0];   // M*N elements, divisible by 128
    const long long n_groups = MN / 128;

    float* y     = (float*)d_out;
    float* scale = y + MN;                         // outputs concatenated: y then scale

    const int threads = 256;                       // 4 waves; 16 groups per iteration
    const long long tiles = (n_groups + 15) / 16;
    long long blocks = tiles < 2048 ? tiles : 2048;   // 256 CU x 8 blocks, grid-stride

    quant_v2_kernel<<<(int)blocks, threads, 0, stream>>>(d_in[0], y, scale, n_groups);
}